// Round 7
// baseline (424.769 us; speedup 1.0000x reference)
//
#include <hip/hip_runtime.h>

// TAACTD loss: reverse-time affine recurrence over T=256, B=65536.
// out[t] = (ret_t - value[t])^2 for t in [0, T-2]; out[T-1] = 0.
// ret_t = acc_{t+1} * (discount[t+1]*GAMMA) + reward[t+1]
// acc_t = il_t ? target_value[t] : ret_t
// il_t  = (step_type[t]==2) | ((t>0) & (rollout_b[t]|b[t]))
//
// Round 7: TLP instead of ILP. Rounds 2/3/6 proved the compiler always
// collapses register pipelines (VGPR 68/44/56), pinning BW at ~2 TB/s with
// 2-4 waves/CU. Fix: split time into C=8 chunks of L=32 steps. A block
// resolves its incoming accumulator EXACTLY by scanning upward from its
// boundary: il=1 (prob ~5/6 per step) makes acc = target_value[t],
// truncating the dependency. Expected scan ~4 rows/wave; worst case runs
// to t=254 where acc = target_value[255] (base) -> always exact.
// Grid: 8 chunks x 128 col-groups = 1024 blocks x 256 thr = 16 waves/CU.

#define GAMMA_F 0.98f

constexpr int T = 256;
constexpr int B = 65536;
constexpr int S = B / 2;        // row stride in float2 units
constexpr int C = 8;            // time chunks
constexpr int L = T / C;        // 32 steps per chunk (top chunk: 31)
constexpr int COLB = S / 256;   // 128 column-groups of 256 threads

typedef float f32x2 __attribute__((ext_vector_type(2)));
typedef int   i32x2 __attribute__((ext_vector_type(2)));

__global__ __launch_bounds__(256) void td_loss_kernel(
    const float* __restrict__ reward,
    const float* __restrict__ discount,
    const float* __restrict__ value,
    const float* __restrict__ target_value,
    const int*   __restrict__ b_arr,
    const int*   __restrict__ rollout_b,
    const int*   __restrict__ step_type,
    float*       __restrict__ out)
{
    const int lane = (blockIdx.x & (COLB - 1)) * 256 + threadIdx.x;  // 0..32767
    const int c    = blockIdx.x >> 7;                                 // chunk 0..7

    const f32x2* rw2 = (const f32x2*)reward;
    const f32x2* dc2 = (const f32x2*)discount;
    const f32x2* vl2 = (const f32x2*)value;
    const f32x2* tv2 = (const f32x2*)target_value;
    const i32x2* b2  = (const i32x2*)b_arr;
    const i32x2* rb2 = (const i32x2*)rollout_b;
    const i32x2* st2 = (const i32x2*)step_type;
    f32x2*       ot2 = (f32x2*)out;

    f32x2 acc;
    int tend;

    if (c == C - 1) {
        // top chunk: incoming acc is the scan init; also zero the last row
        acc = tv2[(size_t)(T - 1) * S + lane];
        f32x2 z; z.x = 0.0f; z.y = 0.0f;
        ot2[(size_t)(T - 1) * S + lane] = z;
        tend = T - 2;                      // 254
    } else {
        // ---- resolve acc at boundary p = (c+1)*L (value after step p) ----
        const int p = (c + 1) * L;

        // scan up: per-component first reset t* (255 = none -> base row)
        int  tsx = T - 1, tsy = T - 1;
        bool rx = false, ry = false;
        for (int t = p; t <= T - 2; ++t) {
            const size_t it = (size_t)t * S + lane;
            const i32x2 st = st2[it];
            const i32x2 bb = b2[it];
            const i32x2 rb = rb2[it];
            const bool ilx = (st.x == 2) || ((bb.x | rb.x) != 0);  // t >= 32 > 0
            const bool ily = (st.y == 2) || ((bb.y | rb.y) != 0);
            if (ilx && !rx) { tsx = t; rx = true; }
            if (ily && !ry) { tsy = t; ry = true; }
            if (__all(rx && ry)) break;    // wave-uniform exit
        }

        // start values at the reset rows (small per-lane gather)
        float ax = target_value[(size_t)tsx * B + 2 * lane];
        float ay = target_value[(size_t)tsy * B + 2 * lane + 1];

        // down-walk from (wave-max t*) - 1 to p, predicated per component;
        // rows are wave-uniform -> coalesced loads
        int tm = (tsx > tsy) ? tsx : tsy;
        #pragma unroll
        for (int off = 32; off > 0; off >>= 1) {
            const int o = __shfl_xor(tm, off);
            tm = (o > tm) ? o : tm;
        }
        for (int t = tm - 1; t >= p; --t) {
            const size_t in = (size_t)(t + 1) * S + lane;
            const f32x2 dn = dc2[in];
            const f32x2 rn = rw2[in];
            if (t < tsx) ax = ax * (dn.x * GAMMA_F) + rn.x;
            if (t < tsy) ay = ay * (dn.y * GAMMA_F) + rn.y;
        }
        acc.x = ax; acc.y = ay;
        tend = p - 1;
    }

    // ---- main streamed chunk: t = tend down to c*L ----
    const int tlo = c * L;
    for (int t = tend; t >= tlo; --t) {
        const size_t it = (size_t)t * S + lane;
        const size_t in = it + S;
        const f32x2 dn = dc2[in];
        const f32x2 rn = rw2[in];
        const f32x2 vv = vl2[it];
        const f32x2 tv = tv2[it];
        const i32x2 st = st2[it];
        const i32x2 bb = b2[it];
        const i32x2 rb = rb2[it];

        const float retx = acc.x * (dn.x * GAMMA_F) + rn.x;
        const float rety = acc.y * (dn.y * GAMMA_F) + rn.y;
        const bool t0  = (t > 0);
        const bool ilx = (st.x == 2) || (t0 && ((bb.x | rb.x) != 0));
        const bool ily = (st.y == 2) || (t0 && ((bb.y | rb.y) != 0));
        acc.x = ilx ? tv.x : retx;
        acc.y = ily ? tv.y : rety;

        f32x2 o;
        o.x = (retx - vv.x) * (retx - vv.x);
        o.y = (rety - vv.y) * (rety - vv.y);
        ot2[it] = o;
    }
}

extern "C" void kernel_launch(void* const* d_in, const int* in_sizes, int n_in,
                              void* d_out, int out_size, void* d_ws, size_t ws_size,
                              hipStream_t stream) {
    const float* reward       = (const float*)d_in[0];
    const float* discount     = (const float*)d_in[1];
    const float* value        = (const float*)d_in[2];
    const float* target_value = (const float*)d_in[3];
    const int*   b_arr        = (const int*)d_in[4];
    const int*   rollout_b    = (const int*)d_in[5];
    const int*   step_type    = (const int*)d_in[6];
    float*       out          = (float*)d_out;

    // 8 chunks x 128 col-groups = 1024 blocks x 256 thr = 4096 waves (16/CU)
    const int blocks = C * COLB;
    td_loss_kernel<<<blocks, 256, 0, stream>>>(
        reward, discount, value, target_value, b_arr, rollout_b, step_type, out);
}